// Round 2
// 875.371 us; speedup vs baseline: 1.3575x; 1.3575x over previous
//
#include <hip/hip_runtime.h>

// RGAT layer, MI355X gfx950. I/O dtype: fp32 per the reference; internals fp32;
// workspace intermediates bf16-packed.
//
// Structure (4 kernels this round):
//  k_prep: W1,W2 fp32 -> bf16 in ws (weights tiny, ~3us, L2-resident after)
//  k_qkv : q,k,v = x@W{q,k,v}^T (+bq)      -> ws qkv[N][384] bf16   (VALU, unchanged)
//  k_attn: edge attention + Wo + res + LN1 -> ws hbuf[N][128] bf16  (VALU, unchanged)
//  k_ffn : FUSED MFMA FFN: hid = relu(h@W1^T+b1) in swizzled LDS (bf16),
//          out = LN2(h + hid@W2^T + b2)    -> d_out fp32
//          M-tile=32 nodes, 4 waves, v_mfma_f32_16x16x32_bf16, 128 MFMA/wave.
//          Eliminates the 102 MB hid round-trip of the old ffn1/ffn2 pair.
//
// R1 fix: k_ffn h-tile staging mixed element/byte offsets -> half of each LDS
// row unstaged -> NaN. Now stages full 256 B/row (8 thr/row x 2 uint4).

typedef unsigned short bf16;  // raw bf16 bits (workspace storage)
typedef unsigned int uint;
typedef __attribute__((ext_vector_type(8))) short short8;   // 8 bf16 = 4 VGPR (MFMA A/B frag)
typedef __attribute__((ext_vector_type(4))) float f32x4;    // MFMA C/D frag

#define NN 50000
#define DEG 16
#define NTILE 16   // nodes per block for VALU kernels; 50000/16 = 3125 exact
#define MT 32      // nodes per block for MFMA ffn; grid 1563 (tail-guarded)

__device__ __forceinline__ float blo(uint u) { return __uint_as_float(u << 16); }
__device__ __forceinline__ float bhi(uint u) { return __uint_as_float(u & 0xffff0000u); }

__device__ __forceinline__ uint f2bfbits(float f) {  // RTN-even
  uint u = __float_as_uint(f);
  return (u + 0x7fffu + ((u >> 16) & 1u)) >> 16;
}
__device__ __forceinline__ uint pack2(float a, float b) {
  return f2bfbits(a) | (f2bfbits(b) << 16);
}
__device__ __forceinline__ void unpack8(uint4 r, float* f) {
  f[0] = blo(r.x); f[1] = bhi(r.x);
  f[2] = blo(r.y); f[3] = bhi(r.y);
  f[4] = blo(r.z); f[5] = bhi(r.z);
  f[6] = blo(r.w); f[7] = bhi(r.w);
}
__device__ __forceinline__ float fma4(float4 w, float4 v, float acc) {
  acc = fmaf(w.x, v.x, acc); acc = fmaf(w.y, v.y, acc);
  acc = fmaf(w.z, v.z, acc); acc = fmaf(w.w, v.w, acc);
  return acc;
}

// ---------------- K0: weight bf16 pre-convert ----------------------------
// W1: 512x128, W2: 128x512 (65536 each). grid 64 x 256, 4 elems/thread each.
__global__ __launch_bounds__(256) void k_prep(
    const float* __restrict__ W1, const float* __restrict__ W2,
    bf16* __restrict__ W1b, bf16* __restrict__ W2b) {
  int i = (blockIdx.x * 256 + threadIdx.x) * 4;
  float4 a = *(const float4*)(W1 + i);
  float4 b = *(const float4*)(W2 + i);
  *(uint2*)(W1b + i) = make_uint2(pack2(a.x, a.y), pack2(a.z, a.w));
  *(uint2*)(W2b + i) = make_uint2(pack2(b.x, b.y), pack2(b.z, b.w));
}

// ---------------- K1: qkv projection (unchanged) -------------------------
__global__ __launch_bounds__(64) void k_qkv(
    const float* __restrict__ x, const float* __restrict__ Wq,
    const float* __restrict__ bq, const float* __restrict__ Wk,
    const float* __restrict__ Wv, bf16* __restrict__ qkv) {
  const int n0 = blockIdx.x * NTILE;
  const int t = threadIdx.x;
  const int d0 = 2 * t;
  __shared__ float4 xs4[NTILE * 32];  // 16 nodes x 128 fp32 = 8KB
  {
    const float4* xg = (const float4*)(x + (size_t)n0 * 128);
    for (int i = t; i < NTILE * 32; i += 64) xs4[i] = xg[i];
  }
  __syncthreads();
  float aq0[NTILE], aq1[NTILE], ak0[NTILE], ak1[NTILE], av0[NTILE], av1[NTILE];
#pragma unroll
  for (int i = 0; i < NTILE; ++i) { aq0[i]=0.f; aq1[i]=0.f; ak0[i]=0.f; ak1[i]=0.f; av0[i]=0.f; av1[i]=0.f; }
  const float4* pq0 = (const float4*)(Wq + (size_t)d0 * 128);
  const float4* pq1 = (const float4*)(Wq + (size_t)(d0 + 1) * 128);
  const float4* pk0 = (const float4*)(Wk + (size_t)d0 * 128);
  const float4* pk1 = (const float4*)(Wk + (size_t)(d0 + 1) * 128);
  const float4* pv0 = (const float4*)(Wv + (size_t)d0 * 128);
  const float4* pv1 = (const float4*)(Wv + (size_t)(d0 + 1) * 128);
  for (int c = 0; c < 32; ++c) {
    float4 wq0 = pq0[c], wq1 = pq1[c];
    float4 wk0 = pk0[c], wk1 = pk1[c];
    float4 wv0 = pv0[c], wv1 = pv1[c];
#pragma unroll
    for (int i = 0; i < NTILE; ++i) {
      float4 xr = xs4[i * 32 + c];   // wave-broadcast, conflict-free
      aq0[i] = fma4(wq0, xr, aq0[i]); aq1[i] = fma4(wq1, xr, aq1[i]);
      ak0[i] = fma4(wk0, xr, ak0[i]); ak1[i] = fma4(wk1, xr, ak1[i]);
      av0[i] = fma4(wv0, xr, av0[i]); av1[i] = fma4(wv1, xr, av1[i]);
    }
  }
  float2 bqv = *(const float2*)(bq + d0);
  for (int i = 0; i < NTILE; ++i) {
    size_t base = (size_t)(n0 + i) * 384;
    *(uint*)(qkv + base + d0)       = pack2(aq0[i] + bqv.x, aq1[i] + bqv.y);
    *(uint*)(qkv + base + 128 + d0) = pack2(ak0[i], ak1[i]);
    *(uint*)(qkv + base + 256 + d0) = pack2(av0[i], av1[i]);
  }
}

// ---------------- K2: edge attention + Wo + residual + LN1 (unchanged) ---
__global__ __launch_bounds__(64) void k_attn(
    const float* __restrict__ x, const float* __restrict__ lgx,
    const int* __restrict__ esrc, const bf16* __restrict__ qkv,
    const float* __restrict__ Wo, const float* __restrict__ bo,
    const float* __restrict__ g1, const float* __restrict__ b1l,
    bf16* __restrict__ hbuf) {
  const int n0 = blockIdx.x * NTILE;
  const int t = threadIdx.x;
  const int d0 = 2 * t;
  __shared__ float4 ot4[NTILE * 32];   // o tiles fp32: 16 nodes x 128 = 8KB
  __shared__ float vt[NTILE][132];     // pre-LN values (pad 132)
  __shared__ float lnm[NTILE], lnr[NTILE];

  for (int i = 0; i < NTILE; ++i) {
    const int n = n0 + i;
    uint qraw = *(const uint*)(qkv + (size_t)n * 384 + d0);
    float q0 = blo(qraw), q1 = bhi(qraw);
    float wv0 = 0.f, wv1 = 0.f, z = 0.f;
#pragma unroll 4
    for (int j = 0; j < DEG; ++j) {
      size_t e = (size_t)n * DEG + j;
      int s = esrc[e];
      uint kraw = *(const uint*)(qkv + (size_t)s * 384 + 128 + d0);
      uint vraw = *(const uint*)(qkv + (size_t)s * 384 + 256 + d0);
      float2 ev = *(const float2*)(lgx + e * 128 + d0);
      float tt = (blo(kraw) + ev.x) * q0 + (bhi(kraw) + ev.y) * q1;
      tt += __shfl_xor(tt, 1); tt += __shfl_xor(tt, 2); tt += __shfl_xor(tt, 4);
      float sc = expf(fminf(fmaxf(tt * 0.25f, -10.f), 10.f));
      wv0 = fmaf(blo(vraw) + ev.x, sc, wv0);
      wv1 = fmaf(bhi(vraw) + ev.y, sc, wv1);
      z += sc;
    }
    float iz = 1.f / z;
    ((float2*)ot4)[i * 64 + t] = make_float2(wv0 * iz, wv1 * iz);
  }
  __syncthreads();
  // Wo matvec: rows d0,d0+1
  float a0[NTILE], a1[NTILE];
#pragma unroll
  for (int i = 0; i < NTILE; ++i) { a0[i] = 0.f; a1[i] = 0.f; }
  const float4* p0 = (const float4*)(Wo + (size_t)d0 * 128);
  const float4* p1 = (const float4*)(Wo + (size_t)(d0 + 1) * 128);
  for (int c = 0; c < 32; ++c) {
    float4 w0 = p0[c], w1 = p1[c];
#pragma unroll
    for (int i = 0; i < NTILE; ++i) {
      float4 orv = ot4[i * 32 + c];
      a0[i] = fma4(w0, orv, a0[i]); a1[i] = fma4(w1, orv, a1[i]);
    }
  }
  float2 bov = *(const float2*)(bo + d0);
  for (int i = 0; i < NTILE; ++i) {
    float2 xr = *(const float2*)(x + (size_t)(n0 + i) * 128 + d0);
    vt[i][d0]     = a0[i] + bov.x + xr.x;
    vt[i][d0 + 1] = a1[i] + bov.y + xr.y;
  }
  __syncthreads();
  {
    int r = t >> 2, qq = t & 3;
    float s = 0.f, s2 = 0.f;
#pragma unroll
    for (int i = 0; i < 32; ++i) { float v = vt[r][qq + 4 * i]; s += v; s2 += v * v; }
    s += __shfl_xor(s, 1); s2 += __shfl_xor(s2, 1);
    s += __shfl_xor(s, 2); s2 += __shfl_xor(s2, 2);
    if (qq == 0) {
      float m = s * 0.0078125f;
      lnm[r] = m;
      lnr[r] = rsqrtf(s2 * 0.0078125f - m * m + 1e-5f);
    }
  }
  __syncthreads();
  float2 gv = *(const float2*)(g1 + d0);
  float2 cv = *(const float2*)(b1l + d0);
  for (int i = 0; i < NTILE; ++i) {
    float o0 = (vt[i][d0] - lnm[i]) * lnr[i] * gv.x + cv.x;
    float o1 = (vt[i][d0 + 1] - lnm[i]) * lnr[i] * gv.y + cv.y;
    *(uint*)(hbuf + (size_t)(n0 + i) * 128 + d0) = pack2(o0, o1);
  }
}

// ---------------- K3: fused MFMA FFN + residual + LN2 --------------------
// block 256 (4 waves). M-tile 32 nodes. Wave w:
//   GEMM1 (N=512,K=128): owns hid cols [w*128, w*128+128) -> 2m x 8n frags, 64 MFMA
//   GEMM2 (N=128,K=512): owns out cols [w*32,  w*32+32)   -> 2m x 2n frags, 64 MFMA
// LDS: hs = h tile [32][128] bf16, XOR-swizzled (byte ^= (row&7)<<4 within row)
//      hidb = hid tile [32][512] bf16, XOR-swizzled; aliased by vt[32][132] fp32
// A-frag: lane l holds A[row=l&15][k=(l>>4)*8 + j]  (8 contiguous bf16 = 1 b128 read)
// B-frag: lane l holds W[col=n0+(l&15)][k=(l>>4)*8 + j] (16B from L2-resident W)
// D-frag: col=lane&15, row=(lane>>4)*4+reg  (m89-verified layout)
__global__ __launch_bounds__(256) void k_ffn(
    const bf16* __restrict__ hbuf, const bf16* __restrict__ W1b,
    const float* __restrict__ b1, const bf16* __restrict__ W2b,
    const float* __restrict__ b2, const float* __restrict__ g2,
    const float* __restrict__ b2l, float* __restrict__ out) {
  const int n0 = blockIdx.x * MT;
  const int t = threadIdx.x;
  const int w = t >> 6, l = t & 63;
  const int lr = l & 15, lk = l >> 4;

  __shared__ __align__(16) char hs[MT * 256];     // 8 KB  h tile (bf16, swizzled)
  __shared__ __align__(16) char hidb[MT * 1024];  // 32 KB hid tile (bf16, swizzled)
  float (*vt)[132] = (float (*)[132])hidb;        // aliased after GEMM2 reads complete
  __shared__ float lnm[MT], lnr[MT];

  // ---- stage h tile (32 rows x 256 bytes), reg-staged so we can swizzle.
  // 8 threads/row, each moves 32 B (elements seg*16..seg*16+15) as 2x uint4.
  {
    int r = t >> 3, seg = t & 7;
    int node = n0 + r; if (node >= NN) node = NN - 1;  // tail clamp (reads only)
    const uint4* src = (const uint4*)(hbuf + (size_t)node * 128 + seg * 16);
    uint4 h0 = src[0], h1 = src[1];
    const int swz = (r & 7) << 4;
    *(uint4*)(hs + r * 256 + ((seg * 32) ^ swz))      = h0;
    *(uint4*)(hs + r * 256 + ((seg * 32 + 16) ^ swz)) = h1;
  }
  __syncthreads();

  // ---- GEMM1: hid = relu(h @ W1^T + b1)
  f32x4 acc1[2][8];
#pragma unroll
  for (int mi = 0; mi < 2; ++mi)
#pragma unroll
    for (int ni = 0; ni < 8; ++ni) acc1[mi][ni] = (f32x4){0.f, 0.f, 0.f, 0.f};
#pragma unroll
  for (int kk = 0; kk < 4; ++kk) {
    const int kb = kk * 64 + lk * 16;  // byte offset of this lane's 8 bf16 within row
    const int r0 = lr, r1 = 16 + lr;
    short8 a0 = *(const short8*)(hs + r0 * 256 + (kb ^ ((r0 & 7) << 4)));
    short8 a1 = *(const short8*)(hs + r1 * 256 + (kb ^ ((r1 & 7) << 4)));
#pragma unroll
    for (int ni = 0; ni < 8; ++ni) {
      int col = w * 128 + ni * 16 + lr;
      short8 b = *(const short8*)(W1b + (size_t)col * 128 + kk * 32 + lk * 8);
      acc1[0][ni] = __builtin_amdgcn_mfma_f32_16x16x32_bf16(a0, b, acc1[0][ni], 0, 0, 0);
      acc1[1][ni] = __builtin_amdgcn_mfma_f32_16x16x32_bf16(a1, b, acc1[1][ni], 0, 0, 0);
    }
  }
  // bias + relu + pack bf16 -> swizzled hid LDS
#pragma unroll
  for (int ni = 0; ni < 8; ++ni) {
    int col = w * 128 + ni * 16 + lr;
    float bias = b1[col];
#pragma unroll
    for (int mi = 0; mi < 2; ++mi)
#pragma unroll
      for (int r = 0; r < 4; ++r) {
        int row = mi * 16 + lk * 4 + r;
        float v = fmaxf(acc1[mi][ni][r] + bias, 0.f);
        *(unsigned short*)(hidb + row * 1024 + ((col * 2) ^ ((row & 7) << 4))) =
            (unsigned short)f2bfbits(v);
      }
  }
  __syncthreads();

  // ---- GEMM2: o2 = hid @ W2^T
  f32x4 acc2[2][2];
#pragma unroll
  for (int mi = 0; mi < 2; ++mi)
#pragma unroll
    for (int ni = 0; ni < 2; ++ni) acc2[mi][ni] = (f32x4){0.f, 0.f, 0.f, 0.f};
#pragma unroll 4
  for (int kk = 0; kk < 16; ++kk) {
    const int kb = kk * 64 + lk * 16;
    const int r0 = lr, r1 = 16 + lr;
    short8 a0 = *(const short8*)(hidb + r0 * 1024 + (kb ^ ((r0 & 7) << 4)));
    short8 a1 = *(const short8*)(hidb + r1 * 1024 + (kb ^ ((r1 & 7) << 4)));
#pragma unroll
    for (int ni = 0; ni < 2; ++ni) {
      int col = w * 32 + ni * 16 + lr;
      short8 b = *(const short8*)(W2b + (size_t)col * 512 + kk * 32 + lk * 8);
      acc2[0][ni] = __builtin_amdgcn_mfma_f32_16x16x32_bf16(a0, b, acc2[0][ni], 0, 0, 0);
      acc2[1][ni] = __builtin_amdgcn_mfma_f32_16x16x32_bf16(a1, b, acc2[1][ni], 0, 0, 0);
    }
  }
  __syncthreads();  // all hid reads done before vt aliases the same LDS

  // ---- vt = o2 + b2 + h (residual)
#pragma unroll
  for (int ni = 0; ni < 2; ++ni) {
    int col = w * 32 + ni * 16 + lr;
    float bias = b2[col];
#pragma unroll
    for (int mi = 0; mi < 2; ++mi)
#pragma unroll
      for (int r = 0; r < 4; ++r) {
        int row = mi * 16 + lk * 4 + r;
        uint hb = *(const unsigned short*)(hs + row * 256 + ((col * 2) ^ ((row & 7) << 4)));
        vt[row][col] = acc2[mi][ni][r] + bias + __uint_as_float(hb << 16);
      }
  }
  __syncthreads();

  // ---- LN2 stats: row r over 8 lanes (qq), 16 cols each
  {
    int r = t >> 3, qq = t & 7;
    float s = 0.f, s2 = 0.f;
#pragma unroll
    for (int i = 0; i < 16; ++i) { float v = vt[r][qq + 8 * i]; s += v; s2 += v * v; }
    s += __shfl_xor(s, 1); s2 += __shfl_xor(s2, 1);
    s += __shfl_xor(s, 2); s2 += __shfl_xor(s2, 2);
    s += __shfl_xor(s, 4); s2 += __shfl_xor(s2, 4);
    if (qq == 0) {
      float m = s * 0.0078125f;
      lnm[r] = m;
      lnr[r] = rsqrtf(s2 * 0.0078125f - m * m + 1e-5f);
    }
  }
  __syncthreads();

  // ---- normalize + coalesced store (thread: row t>>3, 16 cols at (t&7)*16)
  {
    int r = t >> 3, seg = t & 7;
    int node = n0 + r;
    if (node < NN) {
      float m = lnm[r], ir = lnr[r];
#pragma unroll
      for (int j0 = 0; j0 < 16; j0 += 4) {
        int c = seg * 16 + j0;
        float4 gv = *(const float4*)(g2 + c);
        float4 cv = *(const float4*)(b2l + c);
        float4 o;
        o.x = (vt[r][c + 0] - m) * ir * gv.x + cv.x;
        o.y = (vt[r][c + 1] - m) * ir * gv.y + cv.y;
        o.z = (vt[r][c + 2] - m) * ir * gv.z + cv.z;
        o.w = (vt[r][c + 3] - m) * ir * gv.w + cv.w;
        *(float4*)(out + (size_t)node * 128 + c) = o;
      }
    }
  }
}

extern "C" void kernel_launch(void* const* d_in, const int* in_sizes, int n_in,
                              void* d_out, int out_size, void* d_ws, size_t ws_size,
                              hipStream_t stream) {
  const float* x   = (const float*)d_in[0];
  const float* lgx = (const float*)d_in[1];
  const int* esrc  = (const int*)d_in[2];
  // d_in[3] edge_dst unused: dst = e / DEG by construction (repeat(arange(N),DEG))
  const float* Wq  = (const float*)d_in[4];
  const float* bq  = (const float*)d_in[5];
  const float* Wk  = (const float*)d_in[6];
  const float* Wv  = (const float*)d_in[7];
  const float* Wo  = (const float*)d_in[8];
  const float* bo  = (const float*)d_in[9];
  const float* g1  = (const float*)d_in[10];
  const float* b1l = (const float*)d_in[11];
  const float* W1  = (const float*)d_in[12];
  const float* b1  = (const float*)d_in[13];
  const float* W2  = (const float*)d_in[14];
  const float* b2  = (const float*)d_in[15];
  const float* g2  = (const float*)d_in[16];
  const float* b2l = (const float*)d_in[17];

  // ws layout (bf16): qkv[N][384] | hbuf[N][128] | W1b[512*128] | W2b[128*512]
  bf16* qkv  = (bf16*)d_ws;
  bf16* hbuf = qkv + (size_t)NN * 384;
  bf16* W1b  = hbuf + (size_t)NN * 128;
  bf16* W2b  = W1b + 512 * 128;
  float* outp = (float*)d_out;

  const int nblk = NN / NTILE;            // 3125
  const int fblk = (NN + MT - 1) / MT;    // 1563 (tail block has 16 valid rows)
  k_prep<<<dim3(64), dim3(256), 0, stream>>>(W1, W2, W1b, W2b);
  k_qkv<<<dim3(nblk), dim3(64), 0, stream>>>(x, Wq, bq, Wk, Wv, qkv);
  k_attn<<<dim3(nblk), dim3(64), 0, stream>>>(x, lgx, esrc, qkv, Wo, bo, g1, b1l, hbuf);
  k_ffn<<<dim3(fblk), dim3(256), 0, stream>>>(hbuf, W1b, b1, W2b, b2, g2, b2l, outp);
}

// Round 3
// 734.127 us; speedup vs baseline: 1.6187x; 1.1924x over previous
//
#include <hip/hip_runtime.h>

// RGAT layer, MI355X gfx950. I/O dtype: fp32 per the reference; internals fp32;
// workspace intermediates bf16-packed.
//
// Structure (4 kernels this round):
//  k_prep: all 6 weight mats fp32 -> bf16 in ws (tiny, L2-resident after)
//  k_qkv : MFMA q,k,v = x@Wqkv^T (+bq)     -> ws qkv[N][384] bf16
//          (R2: converted from VALU-GEMV to the k_ffn GEMM1 template)
//  k_attn: edge attention (VALU gathers, 8-deep unrolled) + MFMA Wo + res + LN1
//          -> ws hbuf[N][128] bf16  (R2: Wo GEMV -> 1-wave MFMA, esrc preload)
//  k_ffn : fused MFMA FFN (unchanged from R1): hid = relu(h@W1^T+b1) in LDS,
//          out = LN2(h + hid@W2^T + b2)    -> d_out fp32

typedef unsigned short bf16;  // raw bf16 bits (workspace storage)
typedef unsigned int uint;
typedef __attribute__((ext_vector_type(8))) short short8;   // 8 bf16 = 4 VGPR (MFMA A/B frag)
typedef __attribute__((ext_vector_type(4))) float f32x4;    // MFMA C/D frag

#define NN 50000
#define DEG 16
#define NTILE 16   // nodes per block for k_attn; 50000/16 = 3125 exact
#define MT 32      // nodes per block for MFMA kernels; grid 1563 (tail-guarded)

__device__ __forceinline__ float blo(uint u) { return __uint_as_float(u << 16); }
__device__ __forceinline__ float bhi(uint u) { return __uint_as_float(u & 0xffff0000u); }

__device__ __forceinline__ uint f2bfbits(float f) {  // RTN-even
  uint u = __float_as_uint(f);
  return (u + 0x7fffu + ((u >> 16) & 1u)) >> 16;
}
__device__ __forceinline__ uint pack2(float a, float b) {
  return f2bfbits(a) | (f2bfbits(b) << 16);
}

// ---------------- K0: weight bf16 pre-convert ----------------------------
// W1 512x128 (64 blk) | W2 128x512 (64) | Wq,Wk,Wv,Wo 128x128 (16 each). grid 192.
__global__ __launch_bounds__(256) void k_prep(
    const float* __restrict__ W1, const float* __restrict__ W2,
    const float* __restrict__ Wq, const float* __restrict__ Wk,
    const float* __restrict__ Wv, const float* __restrict__ Wo,
    bf16* __restrict__ W1b, bf16* __restrict__ W2b,
    bf16* __restrict__ Wqkvb, bf16* __restrict__ Wob) {
  int b = blockIdx.x;
  const float* src; bf16* dst; int base;
  if (b < 64)       { src = W1; dst = W1b;           base = b; }
  else if (b < 128) { src = W2; dst = W2b;           base = b - 64; }
  else if (b < 144) { src = Wq; dst = Wqkvb;         base = b - 128; }
  else if (b < 160) { src = Wk; dst = Wqkvb + 16384; base = b - 144; }
  else if (b < 176) { src = Wv; dst = Wqkvb + 32768; base = b - 160; }
  else              { src = Wo; dst = Wob;           base = b - 176; }
  int i = (base * 256 + (int)threadIdx.x) * 4;
  float4 a = *(const float4*)(src + i);
  *(uint2*)(dst + i) = make_uint2(pack2(a.x, a.y), pack2(a.z, a.w));
}

// ---------------- K1: qkv projection (MFMA) ------------------------------
// block 256 (4 waves), MT=32 nodes. Output 384 cols = 24 n-frags; wave w owns
// frags f = w+4j (j=0..5): 2 each in q,k,v. 48 MFMA/wave.
// Wqkvb is the concatenated [384][128] bf16 weight (rows: q 0-127, k 128-255, v 256-383).
__global__ __launch_bounds__(256) void k_qkv(
    const float* __restrict__ x, const bf16* __restrict__ Wqkvb,
    const float* __restrict__ bq, bf16* __restrict__ qkv) {
  const int n0 = blockIdx.x * MT;
  const int t = threadIdx.x;
  const int w = t >> 6, l = t & 63;
  const int lr = l & 15, lk = l >> 4;
  __shared__ __align__(16) char xs[MT * 256];  // 8 KB x tile (bf16, swizzled)

  // stage x (fp32 -> bf16 swizzled): 8 thr/row, 16 floats each
  {
    int r = t >> 3, seg = t & 7;
    int node = n0 + r; if (node >= NN) node = NN - 1;  // tail clamp (reads only)
    const float4* src = (const float4*)(x + (size_t)node * 128 + seg * 16);
    float4 a = src[0], b = src[1], c = src[2], d = src[3];
    uint4 h0 = make_uint4(pack2(a.x, a.y), pack2(a.z, a.w), pack2(b.x, b.y), pack2(b.z, b.w));
    uint4 h1 = make_uint4(pack2(c.x, c.y), pack2(c.z, c.w), pack2(d.x, d.y), pack2(d.z, d.w));
    const int swz = (r & 7) << 4;
    *(uint4*)(xs + r * 256 + ((seg * 32) ^ swz))      = h0;
    *(uint4*)(xs + r * 256 + ((seg * 32 + 16) ^ swz)) = h1;
  }
  __syncthreads();

  f32x4 acc[2][6];
#pragma unroll
  for (int mi = 0; mi < 2; ++mi)
#pragma unroll
    for (int j = 0; j < 6; ++j) acc[mi][j] = (f32x4){0.f, 0.f, 0.f, 0.f};
#pragma unroll
  for (int kk = 0; kk < 4; ++kk) {
    const int kb = kk * 64 + lk * 16;
    const int r0 = lr, r1 = 16 + lr;
    short8 a0 = *(const short8*)(xs + r0 * 256 + (kb ^ ((r0 & 7) << 4)));
    short8 a1 = *(const short8*)(xs + r1 * 256 + (kb ^ ((r1 & 7) << 4)));
#pragma unroll
    for (int j = 0; j < 6; ++j) {
      int f = w + 4 * j;
      short8 b = *(const short8*)(Wqkvb + (size_t)(f * 16 + lr) * 128 + kk * 32 + lk * 8);
      acc[0][j] = __builtin_amdgcn_mfma_f32_16x16x32_bf16(a0, b, acc[0][j], 0, 0, 0);
      acc[1][j] = __builtin_amdgcn_mfma_f32_16x16x32_bf16(a1, b, acc[1][j], 0, 0, 0);
    }
  }
#pragma unroll
  for (int j = 0; j < 6; ++j) {
    int f = w + 4 * j;
    int col = f * 16 + lr;                      // 0..383
    float bias = 0.f;
    if (col < 128) bias = bq[col];              // q gets +bq; k,v none
#pragma unroll
    for (int mi = 0; mi < 2; ++mi)
#pragma unroll
      for (int r = 0; r < 4; ++r) {
        int row = mi * 16 + lk * 4 + r;
        int node = n0 + row;
        if (node < NN)
          qkv[(size_t)node * 384 + col] = (bf16)f2bfbits(acc[mi][j][r] + bias);
      }
  }
}

// ---------------- K2: edge attention + MFMA Wo + residual + LN1 ----------
// block 64 (1 wave), 16 nodes. Edge part: thread owns dims 2t,2t+1, 8-lane
// head groups; esrc preloaded, 8-deep unroll for gather ILP. o packed bf16
// swizzled -> 1-wave MFMA (M=16,N=128,K=128, 32 MFMA) -> +bo+x -> LN1 -> hbuf.
__global__ __launch_bounds__(64) void k_attn(
    const float* __restrict__ x, const float* __restrict__ lgx,
    const int* __restrict__ esrc, const bf16* __restrict__ qkv,
    const bf16* __restrict__ Wob, const float* __restrict__ bo,
    const float* __restrict__ g1, const float* __restrict__ b1l,
    bf16* __restrict__ hbuf) {
  const int n0 = blockIdx.x * NTILE;
  const int t = threadIdx.x;
  const int d0 = 2 * t;
  const int lr = t & 15, lk = t >> 4;
  __shared__ __align__(16) char obuf[NTILE * 256];  // 4 KB o tile (bf16, swizzled)
  __shared__ float vt[NTILE][132];                  // pre-LN values (pad 132)
  __shared__ float lnm[NTILE], lnr[NTILE];

  for (int i = 0; i < NTILE; ++i) {
    const int n = n0 + i;
    // preload all 16 source ids (wave-uniform values, from L1/L2)
    int4 e0 = *(const int4*)(esrc + (size_t)n * DEG);
    int4 e1 = *(const int4*)(esrc + (size_t)n * DEG + 4);
    int4 e2 = *(const int4*)(esrc + (size_t)n * DEG + 8);
    int4 e3 = *(const int4*)(esrc + (size_t)n * DEG + 12);
    int es[16] = {e0.x, e0.y, e0.z, e0.w, e1.x, e1.y, e1.z, e1.w,
                  e2.x, e2.y, e2.z, e2.w, e3.x, e3.y, e3.z, e3.w};
    uint qraw = *(const uint*)(qkv + (size_t)n * 384 + d0);
    float q0 = blo(qraw), q1 = bhi(qraw);
    float wv0 = 0.f, wv1 = 0.f, z = 0.f;
#pragma unroll 8
    for (int j = 0; j < DEG; ++j) {
      size_t e = (size_t)n * DEG + j;
      int s = es[j];
      uint kraw = *(const uint*)(qkv + (size_t)s * 384 + 128 + d0);
      uint vraw = *(const uint*)(qkv + (size_t)s * 384 + 256 + d0);
      float2 ev = *(const float2*)(lgx + e * 128 + d0);
      float tt = (blo(kraw) + ev.x) * q0 + (bhi(kraw) + ev.y) * q1;
      tt += __shfl_xor(tt, 1); tt += __shfl_xor(tt, 2); tt += __shfl_xor(tt, 4);
      float sc = expf(fminf(fmaxf(tt * 0.25f, -10.f), 10.f));
      wv0 = fmaf(blo(vraw) + ev.x, sc, wv0);
      wv1 = fmaf(bhi(vraw) + ev.y, sc, wv1);
      z += sc;
    }
    float iz = 1.f / z;
    // pack o (2 bf16) into swizzled LDS row i: element d0 at byte 4t
    *(uint*)(obuf + i * 256 + ((4 * t) ^ ((i & 7) << 4))) = pack2(wv0 * iz, wv1 * iz);
  }
  __syncthreads();

  // ---- MFMA: h' = o @ Wo^T  (M=16 nodes, N=128, K=128; single wave)
  f32x4 acc[8];
#pragma unroll
  for (int ni = 0; ni < 8; ++ni) acc[ni] = (f32x4){0.f, 0.f, 0.f, 0.f};
#pragma unroll
  for (int kk = 0; kk < 4; ++kk) {
    const int kb = kk * 64 + lk * 16;
    short8 a = *(const short8*)(obuf + lr * 256 + (kb ^ ((lr & 7) << 4)));
#pragma unroll
    for (int ni = 0; ni < 8; ++ni) {
      short8 b = *(const short8*)(Wob + (size_t)(ni * 16 + lr) * 128 + kk * 32 + lk * 8);
      acc[ni] = __builtin_amdgcn_mfma_f32_16x16x32_bf16(a, b, acc[ni], 0, 0, 0);
    }
  }
  // vt = o@Wo^T + bo + x  (D-frag: col=lane&15, row=(lane>>4)*4+r)
#pragma unroll
  for (int ni = 0; ni < 8; ++ni) {
    int col = ni * 16 + lr;
    float bias = bo[col];
#pragma unroll
    for (int r = 0; r < 4; ++r) {
      int row = lk * 4 + r;
      vt[row][col] = acc[ni][r] + bias + x[(size_t)(n0 + row) * 128 + col];
    }
  }
  __syncthreads();
  {
    int r = t >> 2, qq = t & 3;
    float s = 0.f, s2 = 0.f;
#pragma unroll
    for (int i = 0; i < 32; ++i) { float v = vt[r][qq + 4 * i]; s += v; s2 += v * v; }
    s += __shfl_xor(s, 1); s2 += __shfl_xor(s2, 1);
    s += __shfl_xor(s, 2); s2 += __shfl_xor(s2, 2);
    if (qq == 0) {
      float m = s * 0.0078125f;
      lnm[r] = m;
      lnr[r] = rsqrtf(s2 * 0.0078125f - m * m + 1e-5f);
    }
  }
  __syncthreads();
  float2 gv = *(const float2*)(g1 + d0);
  float2 cv = *(const float2*)(b1l + d0);
  for (int i = 0; i < NTILE; ++i) {
    float o0 = (vt[i][d0] - lnm[i]) * lnr[i] * gv.x + cv.x;
    float o1 = (vt[i][d0 + 1] - lnm[i]) * lnr[i] * gv.y + cv.y;
    *(uint*)(hbuf + (size_t)(n0 + i) * 128 + d0) = pack2(o0, o1);
  }
}

// ---------------- K3: fused MFMA FFN + residual + LN2 (unchanged) --------
__global__ __launch_bounds__(256) void k_ffn(
    const bf16* __restrict__ hbuf, const bf16* __restrict__ W1b,
    const float* __restrict__ b1, const bf16* __restrict__ W2b,
    const float* __restrict__ b2, const float* __restrict__ g2,
    const float* __restrict__ b2l, float* __restrict__ out) {
  const int n0 = blockIdx.x * MT;
  const int t = threadIdx.x;
  const int w = t >> 6, l = t & 63;
  const int lr = l & 15, lk = l >> 4;

  __shared__ __align__(16) char hs[MT * 256];     // 8 KB  h tile (bf16, swizzled)
  __shared__ __align__(16) char hidb[MT * 1024];  // 32 KB hid tile (bf16, swizzled)
  float (*vt)[132] = (float (*)[132])hidb;        // aliased after GEMM2 reads complete
  __shared__ float lnm[MT], lnr[MT];

  // ---- stage h tile (32 rows x 256 bytes): 8 thr/row x 2 uint4
  {
    int r = t >> 3, seg = t & 7;
    int node = n0 + r; if (node >= NN) node = NN - 1;  // tail clamp (reads only)
    const uint4* src = (const uint4*)(hbuf + (size_t)node * 128 + seg * 16);
    uint4 h0 = src[0], h1 = src[1];
    const int swz = (r & 7) << 4;
    *(uint4*)(hs + r * 256 + ((seg * 32) ^ swz))      = h0;
    *(uint4*)(hs + r * 256 + ((seg * 32 + 16) ^ swz)) = h1;
  }
  __syncthreads();

  // ---- GEMM1: hid = relu(h @ W1^T + b1)
  f32x4 acc1[2][8];
#pragma unroll
  for (int mi = 0; mi < 2; ++mi)
#pragma unroll
    for (int ni = 0; ni < 8; ++ni) acc1[mi][ni] = (f32x4){0.f, 0.f, 0.f, 0.f};
#pragma unroll
  for (int kk = 0; kk < 4; ++kk) {
    const int kb = kk * 64 + lk * 16;
    const int r0 = lr, r1 = 16 + lr;
    short8 a0 = *(const short8*)(hs + r0 * 256 + (kb ^ ((r0 & 7) << 4)));
    short8 a1 = *(const short8*)(hs + r1 * 256 + (kb ^ ((r1 & 7) << 4)));
#pragma unroll
    for (int ni = 0; ni < 8; ++ni) {
      int col = w * 128 + ni * 16 + lr;
      short8 b = *(const short8*)(W1b + (size_t)col * 128 + kk * 32 + lk * 8);
      acc1[0][ni] = __builtin_amdgcn_mfma_f32_16x16x32_bf16(a0, b, acc1[0][ni], 0, 0, 0);
      acc1[1][ni] = __builtin_amdgcn_mfma_f32_16x16x32_bf16(a1, b, acc1[1][ni], 0, 0, 0);
    }
  }
  // bias + relu + pack bf16 -> swizzled hid LDS
#pragma unroll
  for (int ni = 0; ni < 8; ++ni) {
    int col = w * 128 + ni * 16 + lr;
    float bias = b1[col];
#pragma unroll
    for (int mi = 0; mi < 2; ++mi)
#pragma unroll
      for (int r = 0; r < 4; ++r) {
        int row = mi * 16 + lk * 4 + r;
        float v = fmaxf(acc1[mi][ni][r] + bias, 0.f);
        *(unsigned short*)(hidb + row * 1024 + ((col * 2) ^ ((row & 7) << 4))) =
            (unsigned short)f2bfbits(v);
      }
  }
  __syncthreads();

  // ---- GEMM2: o2 = hid @ W2^T
  f32x4 acc2[2][2];
#pragma unroll
  for (int mi = 0; mi < 2; ++mi)
#pragma unroll
    for (int ni = 0; ni < 2; ++ni) acc2[mi][ni] = (f32x4){0.f, 0.f, 0.f, 0.f};
#pragma unroll 4
  for (int kk = 0; kk < 16; ++kk) {
    const int kb = kk * 64 + lk * 16;
    const int r0 = lr, r1 = 16 + lr;
    short8 a0 = *(const short8*)(hidb + r0 * 1024 + (kb ^ ((r0 & 7) << 4)));
    short8 a1 = *(const short8*)(hidb + r1 * 1024 + (kb ^ ((r1 & 7) << 4)));
#pragma unroll
    for (int ni = 0; ni < 2; ++ni) {
      int col = w * 32 + ni * 16 + lr;
      short8 b = *(const short8*)(W2b + (size_t)col * 512 + kk * 32 + lk * 8);
      acc2[0][ni] = __builtin_amdgcn_mfma_f32_16x16x32_bf16(a0, b, acc2[0][ni], 0, 0, 0);
      acc2[1][ni] = __builtin_amdgcn_mfma_f32_16x16x32_bf16(a1, b, acc2[1][ni], 0, 0, 0);
    }
  }
  __syncthreads();  // all hid reads done before vt aliases the same LDS

  // ---- vt = o2 + b2 + h (residual)
#pragma unroll
  for (int ni = 0; ni < 2; ++ni) {
    int col = w * 32 + ni * 16 + lr;
    float bias = b2[col];
#pragma unroll
    for (int mi = 0; mi < 2; ++mi)
#pragma unroll
      for (int r = 0; r < 4; ++r) {
        int row = mi * 16 + lk * 4 + r;
        uint hb = *(const unsigned short*)(hs + row * 256 + ((col * 2) ^ ((row & 7) << 4)));
        vt[row][col] = acc2[mi][ni][r] + bias + __uint_as_float(hb << 16);
      }
  }
  __syncthreads();

  // ---- LN2 stats: row r over 8 lanes (qq), 16 cols each
  {
    int r = t >> 3, qq = t & 7;
    float s = 0.f, s2 = 0.f;
#pragma unroll
    for (int i = 0; i < 16; ++i) { float v = vt[r][qq + 8 * i]; s += v; s2 += v * v; }
    s += __shfl_xor(s, 1); s2 += __shfl_xor(s2, 1);
    s += __shfl_xor(s, 2); s2 += __shfl_xor(s2, 2);
    s += __shfl_xor(s, 4); s2 += __shfl_xor(s2, 4);
    if (qq == 0) {
      float m = s * 0.0078125f;
      lnm[r] = m;
      lnr[r] = rsqrtf(s2 * 0.0078125f - m * m + 1e-5f);
    }
  }
  __syncthreads();

  // ---- normalize + coalesced store (thread: row t>>3, 16 cols at (t&7)*16)
  {
    int r = t >> 3, seg = t & 7;
    int node = n0 + r;
    if (node < NN) {
      float m = lnm[r], ir = lnr[r];
#pragma unroll
      for (int j0 = 0; j0 < 16; j0 += 4) {
        int c = seg * 16 + j0;
        float4 gv = *(const float4*)(g2 + c);
        float4 cv = *(const float4*)(b2l + c);
        float4 o;
        o.x = (vt[r][c + 0] - m) * ir * gv.x + cv.x;
        o.y = (vt[r][c + 1] - m) * ir * gv.y + cv.y;
        o.z = (vt[r][c + 2] - m) * ir * gv.z + cv.z;
        o.w = (vt[r][c + 3] - m) * ir * gv.w + cv.w;
        *(float4*)(out + (size_t)node * 128 + c) = o;
      }
    }
  }
}

extern "C" void kernel_launch(void* const* d_in, const int* in_sizes, int n_in,
                              void* d_out, int out_size, void* d_ws, size_t ws_size,
                              hipStream_t stream) {
  const float* x   = (const float*)d_in[0];
  const float* lgx = (const float*)d_in[1];
  const int* esrc  = (const int*)d_in[2];
  // d_in[3] edge_dst unused: dst = e / DEG by construction (repeat(arange(N),DEG))
  const float* Wq  = (const float*)d_in[4];
  const float* bq  = (const float*)d_in[5];
  const float* Wk  = (const float*)d_in[6];
  const float* Wv  = (const float*)d_in[7];
  const float* Wo  = (const float*)d_in[8];
  const float* bo  = (const float*)d_in[9];
  const float* g1  = (const float*)d_in[10];
  const float* b1l = (const float*)d_in[11];
  const float* W1  = (const float*)d_in[12];
  const float* b1  = (const float*)d_in[13];
  const float* W2  = (const float*)d_in[14];
  const float* b2  = (const float*)d_in[15];
  const float* g2  = (const float*)d_in[16];
  const float* b2l = (const float*)d_in[17];

  // ws layout (bf16): qkv[N][384] | hbuf[N][128] | W1b | W2b | Wqkvb(3x128x128) | Wob
  bf16* qkv   = (bf16*)d_ws;
  bf16* hbuf  = qkv + (size_t)NN * 384;
  bf16* W1b   = hbuf + (size_t)NN * 128;
  bf16* W2b   = W1b + 512 * 128;
  bf16* Wqkvb = W2b + 128 * 512;
  bf16* Wob   = Wqkvb + 3 * 128 * 128;
  float* outp = (float*)d_out;

  const int nblk = NN / NTILE;            // 3125
  const int mblk = (NN + MT - 1) / MT;    // 1563 (tail block has 16 valid rows)
  k_prep<<<dim3(192), dim3(256), 0, stream>>>(W1, W2, Wq, Wk, Wv, Wo, W1b, W2b, Wqkvb, Wob);
  k_qkv<<<dim3(mblk), dim3(256), 0, stream>>>(x, Wqkvb, bq, qkv);
  k_attn<<<dim3(nblk), dim3(64), 0, stream>>>(x, lgx, esrc, qkv, Wob, bo, g1, b1l, hbuf);
  k_ffn<<<dim3(mblk), dim3(256), 0, stream>>>(hbuf, W1b, b1, W2b, b2, g2, b2l, outp);
}